// Round 8
// baseline (877.141 us; speedup 1.0000x reference)
//
#include <hip/hip_runtime.h>
#include <hip/hip_bf16.h>
#include <cstdint>

// MoEExperts: x[4096,2048] f32, top-2 of 8 experts,
// w1/w3 [8,2048,4096] (K-major [K][N]), w2 [8,4096,2048], out [4096,2048] f32.
#define T_TOKENS 4096
#define HID      2048
#define INTER    4096
#define NEXP     8
#define TOPK     2
#define NPAIRS   (T_TOKENS * TOPK)          // 8192
#define BMR      256
#define MAXROWS  (NPAIRS + NEXP * BMR)      // 10240
#define NRB2     32                          // worst-case per-expert row-blocks

typedef __attribute__((ext_vector_type(8))) short   short8;
typedef __attribute__((ext_vector_type(4))) float   f32x4;
typedef __attribute__((ext_vector_type(8))) ushort  ushort8v;

static __device__ __forceinline__ ushort f2bf(float f) {
    __hip_bfloat16 b = __float2bfloat16(f);
    return __builtin_bit_cast(ushort, b);
}
static __device__ __forceinline__ float bf2f(ushort u) {
    return __builtin_bit_cast(float, ((uint)u) << 16);
}

typedef const __attribute__((address_space(1))) unsigned char ga_u8;
typedef __attribute__((address_space(3))) unsigned char       la_u8;
static __device__ __forceinline__ void gl_lds16(const void* g, void* l) {
    __builtin_amdgcn_global_load_lds((ga_u8*)g, (la_u8*)l, 16, 0, 0);
}

#define SBAR() do { __builtin_amdgcn_sched_barrier(0); \
                    __builtin_amdgcn_s_barrier(); \
                    __builtin_amdgcn_sched_barrier(0); \
                    asm volatile("" ::: "memory"); } while (0)
#define VMCNT(n) do { asm volatile("s_waitcnt vmcnt(" #n ")" ::: "memory"); \
                      __builtin_amdgcn_sched_barrier(0); } while (0)
#define LGKM0() do { asm volatile("s_waitcnt lgkmcnt(0)" ::: "memory"); \
                     __builtin_amdgcn_sched_barrier(0); } while (0)

// ---------------- routing (pad per-expert lists to 256) --------------------
__global__ void route_kernel(const int* __restrict__ eidx,
                             const float* __restrict__ ew,
                             int* __restrict__ cnt, int* __restrict__ pbase,
                             int* __restrict__ tokl, float* __restrict__ wgtl) {
    __shared__ int s_cnt[NEXP];
    __shared__ int s_pos[NEXP];
    __shared__ int s_base[NEXP];
    int tid = threadIdx.x;
    if (tid < NEXP) { s_cnt[tid] = 0; s_pos[tid] = 0; }
    __syncthreads();
    for (int p = tid; p < NPAIRS; p += blockDim.x)
        atomicAdd(&s_cnt[eidx[p]], 1);
    __syncthreads();
    if (tid == 0) {
        int b = 0;
        for (int e = 0; e < NEXP; ++e) {
            s_base[e] = b;
            cnt[e]    = s_cnt[e];
            pbase[e]  = b;
            b += (s_cnt[e] + BMR - 1) / BMR * BMR;
        }
        pbase[NEXP] = b;
    }
    __syncthreads();
    for (int p = tid; p < NPAIRS; p += blockDim.x) {
        int e   = eidx[p];
        int pos = atomicAdd(&s_pos[e], 1);
        int row = s_base[e] + pos;
        tokl[row] = p >> 1;
        wgtl[row] = ew[p];
    }
}

// ---------------- x fp32 -> bf16 ------------------------------------------
__global__ __launch_bounds__(256) void cvt_x_kernel(const float* __restrict__ x,
                                                    ushort* __restrict__ xbf) {
    int i = (blockIdx.x * 256 + threadIdx.x) * 8;
    float4 a = *reinterpret_cast<const float4*>(x + i);
    float4 b = *reinterpret_cast<const float4*>(x + i + 4);
    ushort8v o;
    o[0] = f2bf(a.x); o[1] = f2bf(a.y); o[2] = f2bf(a.z); o[3] = f2bf(a.w);
    o[4] = f2bf(b.x); o[5] = f2bf(b.y); o[6] = f2bf(b.z); o[7] = f2bf(b.w);
    *reinterpret_cast<ushort8v*>(xbf + i) = o;
}

// ---------------- weight transpose+convert: fp32 [K][N] -> bf16 [N][K] -----
__global__ __launch_bounds__(256) void transpose_cvt_kernel(
        const float* __restrict__ src, ushort* __restrict__ dst,
        int K, int N, int c0, int CN, long estride) {
    int ez = blockIdx.z;
    const float* s = src + (size_t)ez * estride;
    ushort* d = dst + (size_t)ez * CN * K;
    int nb = blockIdx.x * 64 + c0;
    int kb = blockIdx.y * 64;
    __shared__ ushort t[64][72];
    int tid = threadIdx.x;
    int kr = tid >> 2;
    int ns = tid & 3;
    #pragma unroll
    for (int p = 0; p < 4; ++p) {
        int f = ns + p * 4;
        float4 v = *reinterpret_cast<const float4*>(&s[(size_t)(kb + kr) * N + nb + f * 4]);
        t[f * 4 + 0][kr] = f2bf(v.x);
        t[f * 4 + 1][kr] = f2bf(v.y);
        t[f * 4 + 2][kr] = f2bf(v.z);
        t[f * 4 + 3][kr] = f2bf(v.w);
    }
    __syncthreads();
    int nr = tid >> 2;
    #pragma unroll
    for (int p = 0; p < 2; ++p) {
        int ks = ((tid & 3) + p * 4) * 8;
        ushort8v v8 = *reinterpret_cast<const ushort8v*>(&t[nr][ks]);
        *reinterpret_cast<ushort8v*>(&d[(size_t)(nb - c0 + nr) * K + kb + ks]) = v8;
    }
}

// ---------------- unified 256x256 GEMM, never-drain pipeline ---------------
// MODE 0: g = x@w1            -> write g (bf16) into hbuf
// MODE 1: u = x@w3            -> hbuf = silu(hbuf) * u (in place)
// MODE 2: out += wgt * (h@w2) -> atomicAdd into out
template<int MODE>
__global__ __launch_bounds__(512, 2) void gemm_kernel(
        const ushort* __restrict__ Asrc, const ushort* __restrict__ wT,
        const int* __restrict__ cnt, const int* __restrict__ pbase,
        const int* __restrict__ tokl, const float* __restrict__ wgtl,
        ushort* __restrict__ hbuf, float* __restrict__ out,
        int ncb, int c0, int ng) {
    constexpr int K  = (MODE == 2) ? INTER : HID;
    constexpr int NT = K / 64;

    int d = blockIdx.x;
    int xcd = d & 7, q = d >> 3;
    int gq = q / NRB2, rb = q % NRB2;
    int g = gq * 8 + xcd;
    if (g >= ng) return;
    int ez = g / ncb, cb = g - ez * ncb;
    int ce = cnt[ez];
    int r0 = rb * BMR;
    if (r0 >= ce) return;
    int base = pbase[ez];

    __shared__ char lds[131072];

    int tid  = threadIdx.x;
    int lane = tid & 63, wid = tid >> 6;
    int wm = wid >> 2, wn = wid & 3;
    int wr = wm * 128, wc = wn * 64;
    int rlow = lane & 15, khi = lane >> 4;

    // ---- staging pointers (per-thread, pre-swizzled source k-slot) ----
    int rr = tid >> 3;
    int ssl = (tid & 7) ^ (rr & 7);
    const ushort* pA[4];
    #pragma unroll
    for (int i = 0; i < 4; ++i) {
        if constexpr (MODE == 2) {
            pA[i] = Asrc + (size_t)(base + r0 + i * 64 + rr) * K + ssl * 8;
        } else {
            int row = r0 + i * 64 + rr;
            int tok = (row < ce) ? tokl[base + row] : 0;
            pA[i] = Asrc + (size_t)tok * K + ssl * 8;
        }
    }
    size_t wcol = (size_t)ez * ((size_t)ncb * 256) + (size_t)cb * 256;
    const ushort* pB[4];
    #pragma unroll
    for (int i = 0; i < 4; ++i)
        pB[i] = wT + (wcol + i * 64 + rr) * K + ssl * 8;

    // ---- fragment read offsets (kh=0; kh=1 is ^64) ----
    int abase = wm * 16384;
    int bbase = 32768 + (wn >> 1) * 16384;
    int aoff[8], boff[4];
    #pragma unroll
    for (int mi = 0; mi < 8; ++mi) {
        int arow = mi * 16 + rlow;
        aoff[mi] = abase + arow * 128 + ((khi ^ (arow & 7)) << 4);
    }
    #pragma unroll
    for (int ni = 0; ni < 4; ++ni) {
        int brow = (wn & 1) * 64 + ni * 16 + rlow;
        boff[ni] = bbase + brow * 128 + ((khi ^ (brow & 7)) << 4);
    }

    f32x4 acc[8][4];
    #pragma unroll
    for (int i = 0; i < 8; ++i)
        #pragma unroll
        for (int j = 0; j < 4; ++j) acc[i][j] = (f32x4)0.f;

    auto stA = [&](int db, int h, int t) {
        char* d0 = lds + db * 65536 + h * 16384 + tid * 16;
        gl_lds16(pA[h * 2 + 0] + t * 64, d0);
        gl_lds16(pA[h * 2 + 1] + t * 64, d0 + 8192);
    };
    auto stB = [&](int db, int h, int t) {
        char* d0 = lds + db * 65536 + 32768 + h * 16384 + tid * 16;
        gl_lds16(pB[h * 2 + 0] + t * 64, d0);
        gl_lds16(pB[h * 2 + 1] + t * 64, d0 + 8192);
    };

    // ---- prologue: T0 fully (8 loads) + T1's A halves (4 loads) ----
    stA(0, 0, 0); stA(0, 1, 0); stB(0, 0, 0); stB(0, 1, 0);
    stA(1, 0, 1); stA(1, 1, 1);
    VMCNT(4);
    SBAR();

    #pragma unroll 1
    for (int t = 0; t < NT; ++t) {
        int db = t & 1, nb = db ^ 1;
        const char* L = lds + db * 65536;
        int t1 = (t + 1 < NT) ? t + 1 : NT - 1;
        int t2 = (t + 2 < NT) ? t + 2 : NT - 1;
        short8 af0[8], af1[8], bfr[2];

        // ---- Q0: kh0, ni 0-1 ----
        #pragma unroll
        for (int mi = 0; mi < 8; ++mi)
            af0[mi] = *reinterpret_cast<const short8*>(L + aoff[mi]);
        bfr[0] = *reinterpret_cast<const short8*>(L + boff[0]);
        bfr[1] = *reinterpret_cast<const short8*>(L + boff[1]);
        stB(nb, 0, t1);
        SBAR(); LGKM0();
        __builtin_amdgcn_s_setprio(1);
        #pragma unroll
        for (int ni = 0; ni < 2; ++ni)
            #pragma unroll
            for (int mi = 0; mi < 8; ++mi)
                acc[mi][ni] = __builtin_amdgcn_mfma_f32_16x16x32_bf16(af0[mi], bfr[ni], acc[mi][ni], 0, 0, 0);
        __builtin_amdgcn_s_setprio(0);
        SBAR();

        // ---- Q1: kh1, ni 0-1 ----
        #pragma unroll
        for (int mi = 0; mi < 8; ++mi)
            af1[mi] = *reinterpret_cast<const short8*>(L + (aoff[mi] ^ 64));
        bfr[0] = *reinterpret_cast<const short8*>(L + (boff[0] ^ 64));
        bfr[1] = *reinterpret_cast<const short8*>(L + (boff[1] ^ 64));
        stB(nb, 1, t1);
        SBAR(); LGKM0();
        __builtin_amdgcn_s_setprio(1);
        #pragma unroll
        for (int ni = 0; ni < 2; ++ni)
            #pragma unroll
            for (int mi = 0; mi < 8; ++mi)
                acc[mi][ni] = __builtin_amdgcn_mfma_f32_16x16x32_bf16(af1[mi], bfr[ni], acc[mi][ni], 0, 0, 0);
        __builtin_amdgcn_s_setprio(0);
        SBAR();

        // ---- Q2: kh0, ni 2-3 (A region of db now dead -> stage T+2 A0) ----
        bfr[0] = *reinterpret_cast<const short8*>(L + boff[2]);
        bfr[1] = *reinterpret_cast<const short8*>(L + boff[3]);
        stA(db, 0, t2);
        SBAR(); LGKM0();
        __builtin_amdgcn_s_setprio(1);
        #pragma unroll
        for (int ni = 0; ni < 2; ++ni)
            #pragma unroll
            for (int mi = 0; mi < 8; ++mi)
                acc[mi][ni + 2] = __builtin_amdgcn_mfma_f32_16x16x32_bf16(af0[mi], bfr[ni], acc[mi][ni + 2], 0, 0, 0);
        __builtin_amdgcn_s_setprio(0);
        SBAR();

        // ---- Q3: kh1, ni 2-3 ----
        bfr[0] = *reinterpret_cast<const short8*>(L + (boff[2] ^ 64));
        bfr[1] = *reinterpret_cast<const short8*>(L + (boff[3] ^ 64));
        stA(db, 1, t2);
        SBAR(); LGKM0();
        __builtin_amdgcn_s_setprio(1);
        #pragma unroll
        for (int ni = 0; ni < 2; ++ni)
            #pragma unroll
            for (int mi = 0; mi < 8; ++mi)
                acc[mi][ni + 2] = __builtin_amdgcn_mfma_f32_16x16x32_bf16(af1[mi], bfr[ni], acc[mi][ni + 2], 0, 0, 0);
        __builtin_amdgcn_s_setprio(0);
        VMCNT(4);          // next tile's A+B done; tile-after-next's A stays in flight
        SBAR();
    }
    VMCNT(0);

    // ---- epilogue ----
    int colb = c0 + cb * 256 + wc + rlow;
    #pragma unroll
    for (int mi = 0; mi < 8; ++mi) {
        #pragma unroll
        for (int q2 = 0; q2 < 4; ++q2) {
            int r = r0 + wr + mi * 16 + khi * 4 + q2;
            if (r >= ce) continue;
            if constexpr (MODE == 0) {
                ushort* hp = hbuf + (size_t)(base + r) * INTER + colb;
                #pragma unroll
                for (int ni = 0; ni < 4; ++ni)
                    hp[ni * 16] = f2bf(acc[mi][ni][q2]);
            } else if constexpr (MODE == 1) {
                ushort* hp = hbuf + (size_t)(base + r) * INTER + colb;
                #pragma unroll
                for (int ni = 0; ni < 4; ++ni) {
                    float gg = bf2f(hp[ni * 16]);
                    float s  = gg / (1.f + __expf(-gg));
                    hp[ni * 16] = f2bf(s * acc[mi][ni][q2]);
                }
            } else {
                int tok  = tokl[base + r];
                float wv = wgtl[base + r];
                float* op = out + (size_t)tok * HID + colb;
                #pragma unroll
                for (int ni = 0; ni < 4; ++ni)
                    atomicAdd(&op[ni * 16], wv * acc[mi][ni][q2]);
            }
        }
    }
}

extern "C" void kernel_launch(void* const* d_in, const int* in_sizes, int n_in,
                              void* d_out, int out_size, void* d_ws, size_t ws_size,
                              hipStream_t stream) {
    (void)in_sizes; (void)n_in; (void)out_size;
    const float* x   = (const float*)d_in[0];
    const float* ew  = (const float*)d_in[1];
    const float* w1  = (const float*)d_in[2];
    const float* w2  = (const float*)d_in[3];
    const float* w3  = (const float*)d_in[4];
    const int*  eidx = (const int*)d_in[5];
    float* out = (float*)d_out;

    int*   cnt   = (int*)d_ws;
    int*   pbase = cnt + 8;
    int*   tokl  = cnt + 32;
    float* wgtl  = (float*)(tokl + MAXROWS);
    ushort* xbf  = (ushort*)((((uintptr_t)(wgtl + MAXROWS)) + 255) & ~(uintptr_t)255);
    ushort* h    = xbf + (size_t)T_TOKENS * HID;
    ushort* region = h + (size_t)MAXROWS * INTER;
    size_t region_bytes = ws_size - ((char*)region - (char*)d_ws);

    hipMemsetAsync(d_out, 0, (size_t)T_TOKENS * HID * sizeof(float), stream);
    route_kernel<<<1, 256, 0, stream>>>(eidx, ew, cnt, pbase, tokl, wgtl);
    cvt_x_kernel<<<T_TOKENS * HID / 8 / 256, 256, 0, stream>>>(x, xbf);

    const size_t per_e1 = (size_t)2 * INTER * HID * 2;   // 33.55 MB
    const size_t per_e2 = (size_t)HID * INTER * 2;       // 16.78 MB

    // ---- stage 1: transpose w1/w3 + g-pass + u-pass ----
    if (region_bytes >= per_e1) {
        int EG = (int)(region_bytes / per_e1); if (EG > 8) EG = 8;
        for (int g = 0; g < NEXP; g += EG) {
            int ne = (NEXP - g < EG) ? (NEXP - g) : EG;
            ushort* wt1 = region;
            ushort* wt3 = region + (size_t)ne * INTER * HID;
            transpose_cvt_kernel<<<dim3(INTER / 64, HID / 64, ne), 256, 0, stream>>>(
                w1 + (size_t)g * HID * INTER, wt1, HID, INTER, 0, INTER, (long)HID * INTER);
            transpose_cvt_kernel<<<dim3(INTER / 64, HID / 64, ne), 256, 0, stream>>>(
                w3 + (size_t)g * HID * INTER, wt3, HID, INTER, 0, INTER, (long)HID * INTER);
            int ng = ne * (INTER / 256);
            gemm_kernel<0><<<NRB2 * ng, 512, 0, stream>>>(
                xbf, wt1, cnt + g, pbase + g, tokl, wgtl, h, out, INTER / 256, 0, ng);
            gemm_kernel<1><<<NRB2 * ng, 512, 0, stream>>>(
                xbf, wt3, cnt + g, pbase + g, tokl, wgtl, h, out, INTER / 256, 0, ng);
        }
    } else {
        const int CN = 2048;
        for (int e = 0; e < NEXP; ++e) {
            for (int c = 0; c < INTER; c += CN) {
                ushort* wt1 = region;
                ushort* wt3 = region + (size_t)CN * HID;
                transpose_cvt_kernel<<<dim3(CN / 64, HID / 64, 1), 256, 0, stream>>>(
                    w1 + (size_t)e * HID * INTER, wt1, HID, INTER, c, CN, (long)HID * INTER);
                transpose_cvt_kernel<<<dim3(CN / 64, HID / 64, 1), 256, 0, stream>>>(
                    w3 + (size_t)e * HID * INTER, wt3, HID, INTER, c, CN, (long)HID * INTER);
                int ng = CN / 256;
                gemm_kernel<0><<<NRB2 * ng, 512, 0, stream>>>(
                    xbf, wt1, cnt + e, pbase + e, tokl, wgtl, h, out, CN / 256, c, ng);
                gemm_kernel<1><<<NRB2 * ng, 512, 0, stream>>>(
                    xbf, wt3, cnt + e, pbase + e, tokl, wgtl, h, out, CN / 256, c, ng);
            }
        }
    }

    // ---- stage 2: transpose w2 + ffn2 ----
    if (region_bytes >= per_e2) {
        int EG = (int)(region_bytes / per_e2); if (EG > 8) EG = 8;
        for (int g = 0; g < NEXP; g += EG) {
            int ne = (NEXP - g < EG) ? (NEXP - g) : EG;
            ushort* wt2 = region;
            transpose_cvt_kernel<<<dim3(HID / 64, INTER / 64, ne), 256, 0, stream>>>(
                w2 + (size_t)g * INTER * HID, wt2, INTER, HID, 0, HID, (long)INTER * HID);
            int ng = ne * (HID / 256);
            gemm_kernel<2><<<NRB2 * ng, 512, 0, stream>>>(
                h, wt2, cnt + g, pbase + g, tokl, wgtl, h, out, HID / 256, 0, ng);
        }
    } else {
        const int CN = 1024;
        for (int e = 0; e < NEXP; ++e) {
            for (int c = 0; c < HID; c += CN) {
                ushort* wt2 = region;
                transpose_cvt_kernel<<<dim3(CN / 64, INTER / 64, 1), 256, 0, stream>>>(
                    w2 + (size_t)e * INTER * HID, wt2, INTER, HID, c, CN, (long)INTER * HID);
                int ng = CN / 256;
                int ngp = (ng + 7) / 8 * 8;
                gemm_kernel<2><<<NRB2 * ngp, 512, 0, stream>>>(
                    h, wt2, cnt + e, pbase + e, tokl, wgtl, h, out, CN / 256, c, ng);
            }
        }
    }
}